// Round 4
// baseline (853.194 us; speedup 1.0000x reference)
//
#include <hip/hip_runtime.h>
#include <math.h>

#define T_ 8192
#define C_ 512
#define I_ 64
#define E_ 32

static constexpr float NEGMAX = -3.3895313892515355e+38f; // -finfo(bf16).max

typedef float v4f __attribute__((ext_vector_type(4)));

// ---------------- workspace layout (units of 4 bytes) ----------------
static constexpr size_t WS_RW       = 0;                       // T*E f32 routing weights
static constexpr size_t WS_SIMNORM  = (size_t)T_ * E_;         // 64 f32 = 32 doubles
static constexpr size_t WS_MASKBITS = WS_SIMNORM + 64;         // T u32
static constexpr size_t WS_ACOUNT   = WS_MASKBITS + T_;        // 64 u32 (32 used)
static constexpr size_t WS_ALIST    = WS_ACOUNT + 64;          // E*T u32
// total ~2.13 MB

// ---------------- d_out layout (f32 elements) ----------------
static constexpr size_t OUT_FINAL = 0;                               // T*C
static constexpr size_t OUT_FEO   = (size_t)T_ * C_;                 // T*E*C
static constexpr size_t OUT_PAL   = OUT_FEO + (size_t)T_ * E_ * C_;  // T*E
static constexpr size_t OUT_AM    = OUT_PAL + (size_t)T_ * E_;       // T*E

// =====================================================================
// Kernel N: column norms of sim_matrix (C x E), one block, f64 accum
// =====================================================================
__global__ __launch_bounds__(256) void k_simnorm(const float* __restrict__ sim,
                                                 double* __restrict__ simnorm) {
  int e = threadIdx.x & 31, seg = threadIdx.x >> 5; // 8 segments of 64 rows
  double s = 0.0;
  for (int c = seg * 64; c < seg * 64 + 64; ++c) {
    double v = (double)sim[(size_t)c * E_ + e];
    s = fma(v, v, s);
  }
  __shared__ double red[8][32];
  red[seg][e] = s;
  __syncthreads();
  if (threadIdx.x < 32) {
    double tot = 0.0;
    for (int k = 0; k < 8; ++k) tot += red[k][threadIdx.x];
    simnorm[threadIdx.x] = sqrt(tot);
  }
}

// =====================================================================
// Kernel A: gating. One wave per token (4 tokens / 256-thread block).
// lane = h*32 + e; h in {0,1} splits the C=512 dot into halves.
// f64 accumulation: logits feed a top-16 cut; f32 accum error (~1e-7)
// vs the reference's own rounding risks flipping the boundary expert.
// =====================================================================
__global__ __launch_bounds__(256) void k_gate(
    const float* __restrict__ x, const float* __restrict__ sim,
    const float* __restrict__ gates, const double* __restrict__ simnorm,
    float* __restrict__ pal, float* __restrict__ am,
    float* __restrict__ rw, unsigned* __restrict__ maskbits) {
  int lane = threadIdx.x & 63, wv = threadIdx.x >> 6;
  int t = blockIdx.x * 4 + wv;

  __shared__ float xr[4][512];
  const float* xp = x + (size_t)t * C_;
  v4f v0 = *(const v4f*)(xp + lane * 8);
  v4f v1 = *(const v4f*)(xp + lane * 8 + 4);
  *(v4f*)&xr[wv][lane * 8] = v0;
  *(v4f*)&xr[wv][lane * 8 + 4] = v1;
  double ss = (double)v0[0]*v0[0] + (double)v0[1]*v0[1]
            + (double)v0[2]*v0[2] + (double)v0[3]*v0[3]
            + (double)v1[0]*v1[0] + (double)v1[1]*v1[1]
            + (double)v1[2]*v1[2] + (double)v1[3]*v1[3];
  #pragma unroll
  for (int m = 1; m < 64; m <<= 1) ss += __shfl_xor(ss, m, 64);
  __syncthreads();

  int h = lane >> 5, e = lane & 31;
  const float* sp = sim + (size_t)(h * 256) * E_ + e;
  const float* xh = &xr[wv][h * 256];
  double acc = 0.0;
  #pragma unroll 8
  for (int c = 0; c < 256; ++c)
    acc = fma((double)xh[c], (double)sp[(size_t)c * E_], acc);
  acc += __shfl_xor(acc, 32, 64); // combine halves; all lanes hold full dot

  double xn = sqrt(ss); if (xn < 1e-12) xn = 1e-12;
  double sn = simnorm[e]; if (sn < 1e-12) sn = 1e-12;
  float logit = (float)(acc / (xn * sn));
  float sg  = 1.f / (1.f + expf(-gates[e]));
  float pre = logit - sg;
  float gated = fmaxf(pre, 0.f);
  bool act = gated > 0.f;

  unsigned long long bal = __ballot(act);
  bool tok_inactive = ((unsigned)(bal & 0xffffffffull) == 0u); // wave-uniform

  float mask;
  if (tok_inactive) {
    // top-16 by logits; lower index wins ties (jax.lax.top_k semantics)
    int rank = 0;
    #pragma unroll 1
    for (int j2 = 0; j2 < 32; ++j2) {
      float lj = __shfl(logit, j2, 32);
      if (lj > logit || (lj == logit && j2 < e)) ++rank;
    }
    mask = (rank < 16) ? 1.f : 0.f;
  } else {
    mask = act ? 1.f : 0.f;
  }

  float masked = (mask > 0.f) ? gated : NEGMAX;
  float mx = masked;
  #pragma unroll
  for (int m = 1; m < 32; m <<= 1) mx = fmaxf(mx, __shfl_xor(mx, m, 32));
  float ex = expf(masked - mx); // expf(NEG - mx) underflows to exactly 0
  float sum = ex;
  #pragma unroll
  for (int m = 1; m < 32; m <<= 1) sum += __shfl_xor(sum, m, 32);
  float w = ex / sum;

  unsigned mb = (unsigned)(__ballot(mask > 0.f) & 0xffffffffull);
  if (h == 0) {
    pal[(size_t)t * E_ + e] = pre;
    am [(size_t)t * E_ + e] = mask;
    rw [(size_t)t * E_ + e] = w;
    if (e == 0) maskbits[t] = mb;
  }
}

// =====================================================================
// Kernel S: per-expert compacted active-token lists (block-wide scan,
// one block per expert, deterministic ascending order, no atomics).
// =====================================================================
__global__ __launch_bounds__(1024) void k_lists(const unsigned* __restrict__ maskbits,
                                                unsigned* __restrict__ acount,
                                                unsigned* __restrict__ alist) {
  int e = blockIdx.x;
  int tid = threadIdx.x, lane = tid & 63, wv = tid >> 6; // 16 waves
  __shared__ unsigned wcnt[16], woff[16], stotal, sbase;
  if (tid == 0) sbase = 0;
  __syncthreads();
  for (int chunk = 0; chunk < 8; ++chunk) {
    int t = chunk * 1024 + tid;
    bool bit = (maskbits[t] >> e) & 1u;
    unsigned long long bal = __ballot(bit);
    unsigned prefix = (unsigned)__popcll(bal & ((1ull << lane) - 1ull));
    if (lane == 0) wcnt[wv] = (unsigned)__popcll(bal);
    __syncthreads();
    if (tid == 0) {
      unsigned r = 0;
      for (int k = 0; k < 16; ++k) { woff[k] = r; r += wcnt[k]; }
      stotal = r;
    }
    __syncthreads();
    if (bit) alist[(size_t)e * T_ + sbase + woff[wv] + prefix] = (unsigned)t;
    __syncthreads();
    if (tid == 0) sbase += stotal;
    __syncthreads();
  }
  if (tid == 0) acount[e] = sbase;
}

// =====================================================================
// Kernel B: expert GEMMs over compacted active tokens.
// Block = (expert e, chunk of 64 active tokens), 256 threads.
// H(64x64) = X(64x512) @ W1[e];  Y(64x512) = gelu(H) @ W2[e] -> feo rows.
// bid%8 pins an expert group to one XCD so its L2 keeps just 4 experts.
// =====================================================================
__global__ __launch_bounds__(256) void k_expert(
    const float* __restrict__ x, const float* __restrict__ W1,
    const float* __restrict__ W2, const unsigned* __restrict__ acount,
    const unsigned* __restrict__ alist, float* __restrict__ feo) {
  int bid = blockIdx.x;
  int xcd = bid & 7, j = bid >> 3;
  int e = xcd + 8 * (j & 3);   // experts e%8==xcd stay on one XCD
  int chunk = j >> 2;          // 0..127
  unsigned nact = acount[e];
  int start = chunk * 64;
  if ((unsigned)start >= nact) return;
  int nt = min(64, (int)nact - start);

  // LDS arena: [xT 17408 | w1t 16384] aliased by [w2p 32768];  hT 17408
  __shared__ __align__(16) char arena[51200];
  float (*xT)[68] = (float (*)[68])arena;            // X^T tile, padded stride 68
  float* w1t      = (float*)(arena + 17408);         // [64][64]
  float* w2p      = (float*)arena;                   // [64][128], after GEMM1
  float (*hT)[68] = (float (*)[68])(arena + 33792);  // gelu(H)^T, padded
  __shared__ int toks[64];

  int tid = threadIdx.x;
  if (tid < 64) {
    int idx = start + tid;
    toks[tid] = (int)alist[(size_t)e * T_ + ((idx < (int)nact) ? idx : start)];
  }
  __syncthreads();

  int ty = tid >> 4, tx = tid & 15;
  int tl = tid >> 2, m = tid & 3; // staging roles: 4 threads per token row
  const float* xrow = x + (size_t)toks[tl] * C_;

  float acc1[4][4];
  #pragma unroll
  for (int i = 0; i < 4; ++i)
    #pragma unroll
    for (int jj = 0; jj < 4; ++jj) acc1[i][jj] = 0.f;

  for (int kt = 0; kt < 8; ++kt) {
    // stage X^T (64k x 64t)
    const float* xp = xrow + kt * 64 + m * 16;
    #pragma unroll
    for (int q = 0; q < 4; ++q) {
      v4f v = *(const v4f*)(xp + q * 4);
      int kk = m * 16 + q * 4;
      xT[kk + 0][tl] = v[0];
      xT[kk + 1][tl] = v[1];
      xT[kk + 2][tl] = v[2];
      xT[kk + 3][tl] = v[3];
    }
    // stage W1 tile (64k x 64i), already row-major with i contiguous
    const float* wp = W1 + (size_t)e * C_ * I_ + (size_t)kt * 64 * I_;
    #pragma unroll
    for (int q = 0; q < 4; ++q) {
      int flat = q * 1024 + tid * 4;
      *(v4f*)(w1t + flat) = *(const v4f*)(wp + flat);
    }
    __syncthreads();
    #pragma unroll 4
    for (int kk = 0; kk < 64; ++kk) {
      v4f a = *(const v4f*)&xT[kk][ty * 4];
      v4f b = *(const v4f*)(w1t + kk * 64 + tx * 4);
      #pragma unroll
      for (int i = 0; i < 4; ++i)
        #pragma unroll
        for (int jj = 0; jj < 4; ++jj)
          acc1[i][jj] = fmaf(a[i], b[jj], acc1[i][jj]);
    }
    __syncthreads();
  }

  // exact gelu, store transposed for GEMM2
  #pragma unroll
  for (int i = 0; i < 4; ++i)
    #pragma unroll
    for (int jj = 0; jj < 4; ++jj) {
      float v = acc1[i][jj];
      float g = 0.5f * v * (1.f + erff(v * 0.70710678118654752f));
      hT[tx * 4 + jj][ty * 4 + i] = g;
    }
  __syncthreads();

  for (int p = 0; p < 4; ++p) {
    // stage W2 panel (64k x 128c)
    const float* wp2 = W2 + (size_t)e * I_ * C_ + p * 128;
    #pragma unroll
    for (int q = 0; q < 8; ++q) {
      int flat = q * 1024 + tid * 4;
      int kk = flat >> 7, cc = flat & 127;
      *(v4f*)(w2p + flat) = *(const v4f*)(wp2 + (size_t)kk * C_ + cc);
    }
    __syncthreads();

    float accA[4][4], accB[4][4];
    #pragma unroll
    for (int i = 0; i < 4; ++i)
      #pragma unroll
      for (int jj = 0; jj < 4; ++jj) { accA[i][jj] = 0.f; accB[i][jj] = 0.f; }

    #pragma unroll 4
    for (int kk = 0; kk < 64; ++kk) {
      v4f a  = *(const v4f*)&hT[kk][ty * 4];
      v4f b0 = *(const v4f*)(w2p + kk * 128 + tx * 4);
      v4f b1 = *(const v4f*)(w2p + kk * 128 + 64 + tx * 4);
      #pragma unroll
      for (int i = 0; i < 4; ++i) {
        #pragma unroll
        for (int jj = 0; jj < 4; ++jj) {
          accA[i][jj] = fmaf(a[i], b0[jj], accA[i][jj]);
          accB[i][jj] = fmaf(a[i], b1[jj], accB[i][jj]);
        }
      }
    }

    #pragma unroll
    for (int i = 0; i < 4; ++i) {
      int tkn = ty * 4 + i;
      if (tkn < nt) {
        float* op = feo + ((size_t)toks[tkn] * E_ + e) * C_ + p * 128;
        v4f va = {accA[i][0], accA[i][1], accA[i][2], accA[i][3]};
        v4f vb = {accB[i][0], accB[i][1], accB[i][2], accB[i][3]};
        *(v4f*)(op + tx * 4)      = va;
        *(v4f*)(op + 64 + tx * 4) = vb;
      }
    }
    __syncthreads();
  }
}

// =====================================================================
// Kernel C: zero-fill inactive feo rows + final = sum_e rw * feo.
// One wave per token; branch on activity is wave-uniform (no divergence).
// =====================================================================
__global__ __launch_bounds__(256) void k_final(float* __restrict__ feo,
                                               const float* __restrict__ rw,
                                               const unsigned* __restrict__ maskbits,
                                               float* __restrict__ fout) {
  int lane = threadIdx.x & 63, wv = threadIdx.x >> 6;
  int t = blockIdx.x * 4 + wv;
  unsigned bits = maskbits[t];
  float wlane = (lane < 32) ? rw[(size_t)t * E_ + lane] : 0.f;
  v4f acc0 = {0.f, 0.f, 0.f, 0.f};
  v4f acc1 = {0.f, 0.f, 0.f, 0.f};
  v4f zero = {0.f, 0.f, 0.f, 0.f};
  size_t rowbase = (size_t)t * E_ * C_;
  #pragma unroll 1
  for (int e = 0; e < E_; ++e) {
    float we = __shfl(wlane, e, 64);
    float* rp = feo + rowbase + (size_t)e * C_;
    if (bits & (1u << e)) {
      v4f f0 = *(const v4f*)(rp + lane * 4);
      v4f f1 = *(const v4f*)(rp + 256 + lane * 4);
      acc0 += we * f0;
      acc1 += we * f1;
    } else {
      *(v4f*)(rp + lane * 4)       = zero;
      *(v4f*)(rp + 256 + lane * 4) = zero;
    }
  }
  *(v4f*)(fout + (size_t)t * C_ + lane * 4)       = acc0;
  *(v4f*)(fout + (size_t)t * C_ + 256 + lane * 4) = acc1;
}

// =====================================================================
extern "C" void kernel_launch(void* const* d_in, const int* in_sizes, int n_in,
                              void* d_out, int out_size, void* d_ws, size_t ws_size,
                              hipStream_t stream) {
  const float* x     = (const float*)d_in[0]; // hidden_states (T,C)
  const float* sim   = (const float*)d_in[1]; // sim_matrix (C,E)
  const float* gates = (const float*)d_in[2]; // gates (E,)
  const float* W1    = (const float*)d_in[3]; // (E,C,I)
  const float* W2    = (const float*)d_in[4]; // (E,I,C)
  float* out = (float*)d_out;
  float* ws  = (float*)d_ws;

  float*    rw       = ws + WS_RW;
  double*   simnorm  = (double*)(ws + WS_SIMNORM);
  unsigned* maskbits = (unsigned*)(ws + WS_MASKBITS);
  unsigned* acount   = (unsigned*)(ws + WS_ACOUNT);
  unsigned* alist    = (unsigned*)(ws + WS_ALIST);

  k_simnorm<<<1, 256, 0, stream>>>(sim, simnorm);
  k_gate<<<T_ / 4, 256, 0, stream>>>(x, sim, gates, simnorm,
                                     out + OUT_PAL, out + OUT_AM, rw, maskbits);
  k_lists<<<E_, 1024, 0, stream>>>(maskbits, acount, alist);
  k_expert<<<4096, 256, 0, stream>>>(x, W1, W2, acount, alist, out + OUT_FEO);
  k_final<<<T_ / 4, 256, 0, stream>>>(out + OUT_FEO, rw, maskbits, out + OUT_FINAL);
}

// Round 6
// 844.688 us; speedup vs baseline: 1.0101x; 1.0101x over previous
//
#include <hip/hip_runtime.h>
#include <math.h>

#define T_ 8192
#define C_ 512
#define I_ 64
#define E_ 32

static constexpr float NEGMAX = -3.3895313892515355e+38f; // -finfo(bf16).max

typedef float v4f __attribute__((ext_vector_type(4)));
typedef float f32x4 __attribute__((ext_vector_type(4)));
typedef short s16x8 __attribute__((ext_vector_type(8)));
typedef unsigned short u16;
typedef unsigned short u16x4 __attribute__((ext_vector_type(4)));
typedef unsigned short u16x8 __attribute__((ext_vector_type(8)));

// ---------------- workspace layout (units of 4 bytes) ----------------
static constexpr size_t WS_RW       = 0;                       // T*E f32 routing weights
static constexpr size_t WS_SIMNORM  = (size_t)T_ * E_;         // 64 f32 = 32 doubles
static constexpr size_t WS_MASKBITS = WS_SIMNORM + 64;         // T u32
static constexpr size_t WS_ACOUNT   = WS_MASKBITS + T_;        // 64 u32 (32 used)
static constexpr size_t WS_ALIST    = WS_ACOUNT + 64;          // E*T u32

// ---------------- d_out layout (f32 elements) ----------------
static constexpr size_t OUT_FINAL = 0;                               // T*C
static constexpr size_t OUT_FEO   = (size_t)T_ * C_;                 // T*E*C
static constexpr size_t OUT_PAL   = OUT_FEO + (size_t)T_ * E_ * C_;  // T*E
static constexpr size_t OUT_AM    = OUT_PAL + (size_t)T_ * E_;       // T*E

// bf16 split helpers: x = bf2f(hi) + bf2f(lo) + O(2^-17 x)
__device__ inline u16 f2bf(float x) {
  union { float f; unsigned u; } v; v.f = x;
  unsigned r = v.u + 0x7fffu + ((v.u >> 16) & 1u);
  return (u16)(r >> 16);
}
__device__ inline float bf2f(u16 h) {
  union { unsigned u; float f; } v; v.u = ((unsigned)h) << 16;
  return v.f;
}

// =====================================================================
// Kernel N: column norms of sim_matrix (C x E), one block, f64 accum
// =====================================================================
__global__ __launch_bounds__(256) void k_simnorm(const float* __restrict__ sim,
                                                 double* __restrict__ simnorm) {
  int e = threadIdx.x & 31, seg = threadIdx.x >> 5;
  double s = 0.0;
  for (int c = seg * 64; c < seg * 64 + 64; ++c) {
    double v = (double)sim[(size_t)c * E_ + e];
    s = fma(v, v, s);
  }
  __shared__ double red[8][32];
  red[seg][e] = s;
  __syncthreads();
  if (threadIdx.x < 32) {
    double tot = 0.0;
    for (int k = 0; k < 8; ++k) tot += red[k][threadIdx.x];
    simnorm[threadIdx.x] = sqrt(tot);
  }
}

// =====================================================================
// Kernel A: gating. One wave per token; f64-accumulated dots protect
// the top-16 boundary (every token takes the fallback path here).
// =====================================================================
__global__ __launch_bounds__(256) void k_gate(
    const float* __restrict__ x, const float* __restrict__ sim,
    const float* __restrict__ gates, const double* __restrict__ simnorm,
    float* __restrict__ pal, float* __restrict__ am,
    float* __restrict__ rw, unsigned* __restrict__ maskbits) {
  int lane = threadIdx.x & 63, wv = threadIdx.x >> 6;
  int t = blockIdx.x * 4 + wv;

  __shared__ float xr[4][512];
  const float* xp = x + (size_t)t * C_;
  v4f v0 = *(const v4f*)(xp + lane * 8);
  v4f v1 = *(const v4f*)(xp + lane * 8 + 4);
  *(v4f*)&xr[wv][lane * 8] = v0;
  *(v4f*)&xr[wv][lane * 8 + 4] = v1;
  double ss = (double)v0[0]*v0[0] + (double)v0[1]*v0[1]
            + (double)v0[2]*v0[2] + (double)v0[3]*v0[3]
            + (double)v1[0]*v1[0] + (double)v1[1]*v1[1]
            + (double)v1[2]*v1[2] + (double)v1[3]*v1[3];
  #pragma unroll
  for (int m = 1; m < 64; m <<= 1) ss += __shfl_xor(ss, m, 64);
  __syncthreads();

  int h = lane >> 5, e = lane & 31;
  const float* sp = sim + (size_t)(h * 256) * E_ + e;
  const float* xh = &xr[wv][h * 256];
  double acc = 0.0;
  #pragma unroll 8
  for (int c = 0; c < 256; ++c)
    acc = fma((double)xh[c], (double)sp[(size_t)c * E_], acc);
  acc += __shfl_xor(acc, 32, 64);

  double xn = sqrt(ss); if (xn < 1e-12) xn = 1e-12;
  double sn = simnorm[e]; if (sn < 1e-12) sn = 1e-12;
  float logit = (float)(acc / (xn * sn));
  float sg  = 1.f / (1.f + expf(-gates[e]));
  float pre = logit - sg;
  float gated = fmaxf(pre, 0.f);
  bool act = gated > 0.f;

  unsigned long long bal = __ballot(act);
  bool tok_inactive = ((unsigned)(bal & 0xffffffffull) == 0u);

  float mask;
  if (tok_inactive) {
    int rank = 0;
    #pragma unroll 1
    for (int j2 = 0; j2 < 32; ++j2) {
      float lj = __shfl(logit, j2, 32);
      if (lj > logit || (lj == logit && j2 < e)) ++rank;
    }
    mask = (rank < 16) ? 1.f : 0.f;
  } else {
    mask = act ? 1.f : 0.f;
  }

  float masked = (mask > 0.f) ? gated : NEGMAX;
  float mx = masked;
  #pragma unroll
  for (int m = 1; m < 32; m <<= 1) mx = fmaxf(mx, __shfl_xor(mx, m, 32));
  float ex = expf(masked - mx);
  float sum = ex;
  #pragma unroll
  for (int m = 1; m < 32; m <<= 1) sum += __shfl_xor(sum, m, 32);
  float wgt = ex / sum;

  unsigned mb = (unsigned)(__ballot(mask > 0.f) & 0xffffffffull);
  if (h == 0) {
    pal[(size_t)t * E_ + e] = pre;
    am [(size_t)t * E_ + e] = mask;
    rw [(size_t)t * E_ + e] = wgt;
    if (e == 0) maskbits[t] = mb;
  }
}

// =====================================================================
// Kernel S: per-expert compacted active-token lists
// =====================================================================
__global__ __launch_bounds__(1024) void k_lists(const unsigned* __restrict__ maskbits,
                                                unsigned* __restrict__ acount,
                                                unsigned* __restrict__ alist) {
  int e = blockIdx.x;
  int tid = threadIdx.x, lane = tid & 63, wv = tid >> 6;
  __shared__ unsigned wcnt[16], woff[16], stotal, sbase;
  if (tid == 0) sbase = 0;
  __syncthreads();
  for (int chunk = 0; chunk < 8; ++chunk) {
    int t = chunk * 1024 + tid;
    bool bit = (maskbits[t] >> e) & 1u;
    unsigned long long bal = __ballot(bit);
    unsigned prefix = (unsigned)__popcll(bal & ((1ull << lane) - 1ull));
    if (lane == 0) wcnt[wv] = (unsigned)__popcll(bal);
    __syncthreads();
    if (tid == 0) {
      unsigned r = 0;
      for (int k = 0; k < 16; ++k) { woff[k] = r; r += wcnt[k]; }
      stotal = r;
    }
    __syncthreads();
    if (bit) alist[(size_t)e * T_ + sbase + woff[wv] + prefix] = (unsigned)t;
    __syncthreads();
    if (tid == 0) sbase += stotal;
    __syncthreads();
  }
  if (tid == 0) acount[e] = sbase;
}

// =====================================================================
// Kernel B: expert GEMMs via split-bf16 MFMA (hi/lo error compensation).
// Block = (expert e, 64 active tokens), 256 thr = 4 waves.
// G1: H(64tok x 64i) = X(64x512) @ W1[e]; gelu -> gM (bf16 hi/lo in LDS)
// G2: Y(64tok x 512c) = G @ W2[e] -> feo rows.
// Fragment convention (mfma_f32_16x16x32_bf16):
//   a_frag lane l elem j = A[l&15][(l>>4)*8+j]
//   b_frag lane l elem j = B[(l>>4)*8+j][l&15]
//   d lane l reg r       = D[(l>>4)*4+r][l&15]   (guide-verified)
// All LDS tiles row-padded to 72 bf16 (144 B) -> b128 reads spread over
// all 8 bank-slots ((row+unit) mod 8 uniform).
// =====================================================================
__device__ inline f32x4 mfma3(s16x8 ah, s16x8 al, s16x8 bh, s16x8 bl, f32x4 c) {
  c = __builtin_amdgcn_mfma_f32_16x16x32_bf16(ah, bh, c, 0, 0, 0);
  c = __builtin_amdgcn_mfma_f32_16x16x32_bf16(ah, bl, c, 0, 0, 0);
  c = __builtin_amdgcn_mfma_f32_16x16x32_bf16(al, bh, c, 0, 0, 0);
  return c;
}

__global__ __launch_bounds__(256) void k_expert(
    const float* __restrict__ x, const float* __restrict__ W1,
    const float* __restrict__ W2, const unsigned* __restrict__ acount,
    const unsigned* __restrict__ alist, float* __restrict__ feo) {
  int bid = blockIdx.x;
  int xcd = bid & 7, j = bid >> 3;
  int e = xcd + 8 * (j & 3);   // experts e%8==xcd stay on one XCD
  int chunk = j >> 2;          // 0..127
  unsigned nact = acount[e];
  int start = chunk * 64;
  if ((unsigned)start >= nact) return;
  int nt = min(64, (int)nact - start);

  // LDS arena, phase-aliased:
  //   phase1: xs_h 0..9216 | xs_l | w1_h 18432.. | w1_l 27648..36864
  //   phase2: gm_h 0..9216 | gm_l | w2_h 18432..36864 | w2_l 36864..55296
  __shared__ __align__(16) char arena[55296];
  __shared__ int toks[64];
  u16* xs_h = (u16*)arena;             // [64][72]
  u16* xs_l = (u16*)(arena + 9216);
  u16* w1_h = (u16*)(arena + 18432);   // [64 i][72]  (transposed W1)
  u16* w1_l = (u16*)(arena + 27648);
  u16* gm_h = (u16*)arena;             // [64 tok][72]
  u16* gm_l = (u16*)(arena + 9216);
  u16* w2_h = (u16*)(arena + 18432);   // [128 c][72] (transposed W2 panel)
  u16* w2_l = (u16*)(arena + 36864);

  int tid = threadIdx.x;
  int lane = tid & 63, w = tid >> 6;
  int lr = lane & 15, lg = lane >> 4;

  if (tid < 64) {
    int idx = start + tid;
    toks[tid] = (int)alist[(size_t)e * T_ + (idx < (int)nact ? idx : start)];
  }
  __syncthreads();

  // ---------------- GEMM1: K=512 in 8 chunks of 64 ----------------
  f32x4 acc1[4];
  #pragma unroll
  for (int n = 0; n < 4; ++n) acc1[n] = (f32x4){0.f, 0.f, 0.f, 0.f};

  int srow = tid >> 2, su = tid & 3;   // xs staging: token row, 16-f32 unit
  int wiq = tid & 15, wc4 = tid >> 4;  // w1 staging: i-quad, c-quad
  const float* w1b = W1 + (size_t)e * C_ * I_;
  const float* xrow = x + (size_t)toks[srow] * C_;

  for (int kc = 0; kc < 8; ++kc) {
    // stage X rows (gathered) -> xs hi/lo
    {
      const float* src = xrow + kc * 64 + su * 16;
      float f[16];
      *(v4f*)(f)      = *(const v4f*)(src);
      *(v4f*)(f + 4)  = *(const v4f*)(src + 4);
      *(v4f*)(f + 8)  = *(const v4f*)(src + 8);
      *(v4f*)(f + 12) = *(const v4f*)(src + 12);
      u16 h[16], l[16];
      #pragma unroll
      for (int q = 0; q < 16; ++q) {
        h[q] = f2bf(f[q]);
        l[q] = f2bf(f[q] - bf2f(h[q]));
      }
      int off = srow * 72 + su * 16;
      *(u16x8*)(xs_h + off)     = *(u16x8*)(h);
      *(u16x8*)(xs_h + off + 8) = *(u16x8*)(h + 8);
      *(u16x8*)(xs_l + off)     = *(u16x8*)(l);
      *(u16x8*)(xs_l + off + 8) = *(u16x8*)(l + 8);
    }
    // stage W1 tile transposed: read [c][i] 4x4 block, write [i][c]
    {
      const float* src = w1b + (size_t)(kc * 64 + wc4 * 4) * I_ + wiq * 4;
      v4f b0 = *(const v4f*)(src);
      v4f b1 = *(const v4f*)(src + I_);
      v4f b2 = *(const v4f*)(src + 2 * I_);
      v4f b3 = *(const v4f*)(src + 3 * I_);
      #pragma unroll
      for (int ii = 0; ii < 4; ++ii) {
        float c0 = b0[ii], c1 = b1[ii], c2 = b2[ii], c3 = b3[ii];
        u16 h0 = f2bf(c0), h1 = f2bf(c1), h2 = f2bf(c2), h3 = f2bf(c3);
        u16x4 hv = {h0, h1, h2, h3};
        u16x4 lv = {f2bf(c0 - bf2f(h0)), f2bf(c1 - bf2f(h1)),
                    f2bf(c2 - bf2f(h2)), f2bf(c3 - bf2f(h3))};
        int off = (wiq * 4 + ii) * 72 + wc4 * 4;
        *(u16x4*)(w1_h + off) = hv;
        *(u16x4*)(w1_l + off) = lv;
      }
    }
    __syncthreads();
    #pragma unroll
    for (int s = 0; s < 2; ++s) {
      int ko = s * 32 + lg * 8;
      s16x8 ah = *(const s16x8*)(xs_h + (w * 16 + lr) * 72 + ko);
      s16x8 al = *(const s16x8*)(xs_l + (w * 16 + lr) * 72 + ko);
      #pragma unroll
      for (int n = 0; n < 4; ++n) {
        s16x8 bh = *(const s16x8*)(w1_h + (n * 16 + lr) * 72 + ko);
        s16x8 bl = *(const s16x8*)(w1_l + (n * 16 + lr) * 72 + ko);
        acc1[n] = mfma3(ah, al, bh, bl, acc1[n]);
      }
    }
    __syncthreads();
  }

  // gelu + split -> gM (aliases xs region; last barrier protects)
  #pragma unroll
  for (int n = 0; n < 4; ++n) {
    #pragma unroll
    for (int r = 0; r < 4; ++r) {
      float v = acc1[n][r];
      float g = 0.5f * v * (1.f + erff(v * 0.70710678118654752f));
      u16 h = f2bf(g);
      int off = (w * 16 + lg * 4 + r) * 72 + n * 16 + lr;
      gm_h[off] = h;
      gm_l[off] = f2bf(g - bf2f(h));
    }
  }
  __syncthreads();

  // ---------------- GEMM2: panels of 128 c, K=64 ----------------
  const float* w2b = W2 + (size_t)e * I_ * C_;
  for (int p = 0; p < 4; ++p) {
    // stage W2 panel transposed: read [i][c] 4x4 blocks, write [c][i]
    #pragma unroll
    for (int task = tid; task < 512; task += 256) {
      int cq = task >> 4, iq = task & 15;
      const float* src = w2b + (size_t)(iq * 4) * C_ + p * 128 + cq * 4;
      v4f b0 = *(const v4f*)(src);
      v4f b1 = *(const v4f*)(src + C_);
      v4f b2 = *(const v4f*)(src + 2 * C_);
      v4f b3 = *(const v4f*)(src + 3 * C_);
      #pragma unroll
      for (int cc = 0; cc < 4; ++cc) {
        float c0 = b0[cc], c1 = b1[cc], c2 = b2[cc], c3 = b3[cc];
        u16 h0 = f2bf(c0), h1 = f2bf(c1), h2 = f2bf(c2), h3 = f2bf(c3);
        u16x4 hv = {h0, h1, h2, h3};
        u16x4 lv = {f2bf(c0 - bf2f(h0)), f2bf(c1 - bf2f(h1)),
                    f2bf(c2 - bf2f(h2)), f2bf(c3 - bf2f(h3))};
        int off = (cq * 4 + cc) * 72 + iq * 4;
        *(u16x4*)(w2_h + off) = hv;
        *(u16x4*)(w2_l + off) = lv;
      }
    }
    __syncthreads();

    f32x4 acc2[8];
    #pragma unroll
    for (int n = 0; n < 8; ++n) acc2[n] = (f32x4){0.f, 0.f, 0.f, 0.f};
    #pragma unroll
    for (int s = 0; s < 2; ++s) {
      int ko = s * 32 + lg * 8;
      s16x8 ah = *(const s16x8*)(gm_h + (w * 16 + lr) * 72 + ko);
      s16x8 al = *(const s16x8*)(gm_l + (w * 16 + lr) * 72 + ko);
      #pragma unroll
      for (int n = 0; n < 8; ++n) {
        s16x8 bh = *(const s16x8*)(w2_h + (n * 16 + lr) * 72 + ko);
        s16x8 bl = *(const s16x8*)(w2_l + (n * 16 + lr) * 72 + ko);
        acc2[n] = mfma3(ah, al, bh, bl, acc2[n]);
      }
    }
    // store: D[tok][c]: tok = w*16+lg*4+r, c = p*128 + n*16 + lr
    #pragma unroll
    for (int n = 0; n < 8; ++n) {
      #pragma unroll
      for (int r = 0; r < 4; ++r) {
        int slot = w * 16 + lg * 4 + r;
        if (slot < nt) {
          feo[((size_t)toks[slot] * E_ + e) * C_ + p * 128 + n * 16 + lr] =
              acc2[n][r];
        }
      }
    }
    __syncthreads();
  }
}

// =====================================================================
// Kernel C: zero-fill inactive feo rows + final = sum_e rw * feo.
// =====================================================================
__global__ __launch_bounds__(256) void k_final(float* __restrict__ feo,
                                               const float* __restrict__ rw,
                                               const unsigned* __restrict__ maskbits,
                                               float* __restrict__ fout) {
  int lane = threadIdx.x & 63, wv = threadIdx.x >> 6;
  int t = blockIdx.x * 4 + wv;
  unsigned bits = maskbits[t];
  float wlane = (lane < 32) ? rw[(size_t)t * E_ + lane] : 0.f;
  v4f acc0 = {0.f, 0.f, 0.f, 0.f};
  v4f acc1 = {0.f, 0.f, 0.f, 0.f};
  v4f zero = {0.f, 0.f, 0.f, 0.f};
  size_t rowbase = (size_t)t * E_ * C_;
  #pragma unroll 1
  for (int e = 0; e < E_; ++e) {
    float we = __shfl(wlane, e, 64);
    float* rp = feo + rowbase + (size_t)e * C_;
    if (bits & (1u << e)) {
      v4f f0 = *(const v4f*)(rp + lane * 4);
      v4f f1 = *(const v4f*)(rp + 256 + lane * 4);
      acc0 += we * f0;
      acc1 += we * f1;
    } else {
      *(v4f*)(rp + lane * 4)       = zero;
      *(v4f*)(rp + 256 + lane * 4) = zero;
    }
  }
  *(v4f*)(fout + (size_t)t * C_ + lane * 4)       = acc0;
  *(v4f*)(fout + (size_t)t * C_ + 256 + lane * 4) = acc1;
}

// =====================================================================
extern "C" void kernel_launch(void* const* d_in, const int* in_sizes, int n_in,
                              void* d_out, int out_size, void* d_ws, size_t ws_size,
                              hipStream_t stream) {
  const float* x     = (const float*)d_in[0];
  const float* sim   = (const float*)d_in[1];
  const float* gates = (const float*)d_in[2];
  const float* W1    = (const float*)d_in[3];
  const float* W2    = (const float*)d_in[4];
  float* out = (float*)d_out;
  float* ws  = (float*)d_ws;

  float*    rw       = ws + WS_RW;
  double*   simnorm  = (double*)(ws + WS_SIMNORM);
  unsigned* maskbits = (unsigned*)(ws + WS_MASKBITS);
  unsigned* acount   = (unsigned*)(ws + WS_ACOUNT);
  unsigned* alist    = (unsigned*)(ws + WS_ALIST);

  k_simnorm<<<1, 256, 0, stream>>>(sim, simnorm);
  k_gate<<<T_ / 4, 256, 0, stream>>>(x, sim, gates, simnorm,
                                     out + OUT_PAL, out + OUT_AM, rw, maskbits);
  k_lists<<<E_, 1024, 0, stream>>>(maskbits, acount, alist);
  k_expert<<<4096, 256, 0, stream>>>(x, W1, W2, acount, alist, out + OUT_FEO);
  k_final<<<T_ / 4, 256, 0, stream>>>(out + OUT_FEO, rw, maskbits, out + OUT_FINAL);
}